// Round 12
// baseline (274.994 us; speedup 1.0000x reference)
//
#include <hip/hip_runtime.h>

typedef unsigned short u16;
typedef unsigned int u32;
typedef signed char i8;
typedef __bf16 bf16x8 __attribute__((ext_vector_type(8)));
typedef float f32x4 __attribute__((ext_vector_type(4)));
typedef int i32x4 __attribute__((ext_vector_type(4)));
typedef i8 i8x4 __attribute__((ext_vector_type(4)));
typedef u16 u16x8 __attribute__((ext_vector_type(8)));

#define AS1(p) ((const __attribute__((address_space(1))) void*)(p))
#define AS3(p) ((__attribute__((address_space(3))) void*)(p))

__device__ __forceinline__ u16 f2bf(float x) {
  u32 u = __float_as_uint(x);
  u32 r = u + 0x7fffu + ((u >> 16) & 1u);
  return (u16)(r >> 16);
}
__device__ __forceinline__ float bf2f(u16 h) {
  return __uint_as_float(((u32)h) << 16);
}

// ---------------------------------------------------------------------------
// i8 dual-split quantizer: x ~= s*(h + l/256), |err| <= s/512.
// ---------------------------------------------------------------------------
#define S_IN (8.0f / 127.0f)
#define S_W (0.25f / 127.0f)
#define S_QK (8.0f / 127.0f)
#define INV_S_IN (127.0f / 8.0f)
#define INV_S_W (508.0f)
#define INV_S_QK (127.0f / 8.0f)

__device__ __forceinline__ int2 q8i(float x, float inv_s) {
  float t = fminf(fmaxf(x * inv_s, -126.99f), 126.99f);
  float hf = rintf(t);
  float lf = fminf(fmaxf(rintf((t - hf) * 256.0f), -127.0f), 127.0f);
  return make_int2((int)hf, (int)lf);
}

// ---------------------------------------------------------------------------
// prep_all: one launch fusing three independent preprocessing stages.
// ---------------------------------------------------------------------------
__global__ __launch_bounds__(256) void prep_all(
    const float* __restrict__ q, const float* __restrict__ k,
    const float* __restrict__ value, const float* __restrict__ Wq,
    const float* __restrict__ Wo, i8* __restrict__ qh, i8* __restrict__ ql,
    i8* __restrict__ kh, i8* __restrict__ kl, u16* __restrict__ valT,
    i8* __restrict__ wqt_h, i8* __restrict__ wqt_l, u16* __restrict__ wot,
    u16* __restrict__ wq_b) {
  __shared__ float tileA[32][33];
  __shared__ float tileB[32][33];
  const int bid = blockIdx.x;
  const int tid = threadIdx.x;
  const int D = 1024;

  if (bid < 8192) {
    const int bx = bid & 31;
    const int by = (bid >> 5) & 63;
    const int bz = bid >> 11;
    const int tx = tid & 31, ty = tid >> 5;
    const int c0 = bx * 32, r0 = by * 32;
    const size_t zi = (size_t)bz * 2048 * 1024;
#pragma unroll
    for (int i = ty; i < 32; i += 8)
      tileA[i][tx] = value[zi + (size_t)(r0 + i) * D + (c0 + tx)];
    __syncthreads();
#pragma unroll
    for (int i = ty; i < 32; i += 8)
      valT[zi + (size_t)(c0 + i) * 2048 + (r0 + tx)] = f2bf(tileA[tx][i]);
  } else if (bid < 10240) {
    const int b2 = bid - 8192;
    const int n4 = 2097152;
    const int stride = 2048 * 256;
    for (int i = b2 * 256 + tid; i < n4; i += stride) {
      float4 x = ((const float4*)q)[i];
      float xs[4] = {x.x, x.y, x.z, x.w};
      i8x4 h, l;
#pragma unroll
      for (int e = 0; e < 4; ++e) {
        int2 r = q8i(xs[e], INV_S_IN);
        h[e] = (i8)r.x;
        l[e] = (i8)r.y;
      }
      ((i8x4*)qh)[i] = h;
      ((i8x4*)ql)[i] = l;
      x = ((const float4*)k)[i];
      float ys[4] = {x.x, x.y, x.z, x.w};
#pragma unroll
      for (int e = 0; e < 4; ++e) {
        int2 r = q8i(ys[e], INV_S_IN);
        h[e] = (i8)r.x;
        l[e] = (i8)r.y;
      }
      ((i8x4*)kh)[i] = h;
      ((i8x4*)kl)[i] = l;
    }
  } else {
    const int r = bid - 10240;
    const int bx = r & 31, by = r >> 5;
    const int tx = tid & 31, ty = tid >> 5;
    const int c0 = bx * 32, r0 = by * 32;
#pragma unroll
    for (int i = ty; i < 32; i += 8) {
      float xq = Wq[(size_t)(r0 + i) * D + c0 + tx];
      tileA[i][tx] = xq;
      wq_b[(size_t)(r0 + i) * D + c0 + tx] = f2bf(xq);
      tileB[i][tx] = Wo[(size_t)(r0 + i) * D + c0 + tx];
    }
    __syncthreads();
#pragma unroll
    for (int i = ty; i < 32; i += 8) {
      float x = tileA[tx][i];
      int2 rr = q8i(x, INV_S_W);
      size_t o = (size_t)(c0 + i) * D + r0 + tx;
      wqt_h[o] = (i8)rr.x;
      wqt_l[o] = (i8)rr.y;
      wot[o] = f2bf(tileB[tx][i]);
    }
  }
}

// bqo[f] = sum_e bq[e]*Wo[e][f] + bo[f]   via wot (Wo^T bf16).
__global__ __launch_bounds__(256) void bqo_kernel(const float* __restrict__ bq,
                                                  const u16* __restrict__ wot,
                                                  const float* __restrict__ bo,
                                                  float* __restrict__ bqo,
                                                  int D) {
  const int f = blockIdx.x * 4 + (threadIdx.x >> 6);
  const int lane = threadIdx.x & 63;
  const u16* wr_ = wot + (size_t)f * D;
  float s = 0.f;
  for (int e = lane; e < D; e += 64) s += bq[e] * bf2f(wr_[e]);
#pragma unroll
  for (int off = 32; off; off >>= 1) s += __shfl_xor(s, off);
  if (lane == 0) bqo[f] = s + bo[f];
}

// ---------------------------------------------------------------------------
// 128x128 2-barrier GEMM (only for the tiny Wqo GEMM).
// ---------------------------------------------------------------------------
template <int EPI>
__global__ __launch_bounds__(256, 2) void gemm_bt(
    const u16* __restrict__ Ah, const u16* __restrict__ Bh,
    const float* __restrict__ bias, float* __restrict__ Cf,
    u16* __restrict__ Ch, int M, int N, int K,
    long long sA, long long sB, long long sC) {
  __shared__ alignas(16) u16 As[128 * 32];
  __shared__ alignas(16) u16 Bs[128 * 32];

  const int t = threadIdx.x;
  const int lane = t & 63;
  const int w = t >> 6;
  const int wr = w >> 1, wc = w & 1;

  const long long zb = blockIdx.z;
  const u16* pA = Ah + zb * sA;
  const u16* pB = Bh + zb * sB;

  const int m0 = blockIdx.x * 128;
  const int n0 = blockIdx.y * 128;

  f32x4 acc[4][4] = {};

  const int row0 = t >> 2;
  const int colS = (t & 3) * 8;
  const int lds0 = (t & ~63) * 8;
  const int lds1 = (256 + (t & ~63)) * 8;

  const size_t aoff0 = (size_t)(m0 + row0) * K + colS;
  const size_t aoff1 = (size_t)(m0 + row0 + 64) * K + colS;
  const size_t boff0 = (size_t)(n0 + row0) * K + colS;
  const size_t boff1 = (size_t)(n0 + row0 + 64) * K + colS;

  for (int k0 = 0; k0 < K; k0 += 32) {
    __syncthreads();
    __builtin_amdgcn_global_load_lds(AS1(pA + aoff0 + k0), AS3(&As[lds0]), 16, 0, 0);
    __builtin_amdgcn_global_load_lds(AS1(pA + aoff1 + k0), AS3(&As[lds1]), 16, 0, 0);
    __builtin_amdgcn_global_load_lds(AS1(pB + boff0 + k0), AS3(&Bs[lds0]), 16, 0, 0);
    __builtin_amdgcn_global_load_lds(AS1(pB + boff1 + k0), AS3(&Bs[lds1]), 16, 0, 0);
    __syncthreads();

    const int fr = lane & 15;
    const int kc = (lane >> 4) * 8;
    bf16x8 a[4], b[4];
#pragma unroll
    for (int i = 0; i < 4; ++i)
      a[i] = *(const bf16x8*)&As[(wr * 64 + i * 16 + fr) * 32 + kc];
#pragma unroll
    for (int j = 0; j < 4; ++j)
      b[j] = *(const bf16x8*)&Bs[(wc * 64 + j * 16 + fr) * 32 + kc];
#pragma unroll
    for (int i = 0; i < 4; ++i)
#pragma unroll
      for (int j = 0; j < 4; ++j)
        acc[i][j] = __builtin_amdgcn_mfma_f32_16x16x32_bf16(a[i], b[j], acc[i][j], 0, 0, 0);
  }

  const int er = (lane >> 4) * 4;
  const int ec = lane & 15;
#pragma unroll
  for (int j = 0; j < 4; ++j) {
    const int gcol = n0 + wc * 64 + j * 16 + ec;
    const float bv = bias ? bias[gcol] : 0.0f;
#pragma unroll
    for (int i = 0; i < 4; ++i) {
      const int grow0 = m0 + wr * 64 + i * 16 + er;
#pragma unroll
      for (int r = 0; r < 4; ++r) {
        const float x = acc[i][j][r] + bv;
        const size_t off = (size_t)zb * sC + (size_t)(grow0 + r) * N + gcol;
        if constexpr (EPI == 0) Cf[off] = x;
        else Ch[off] = f2bf(x);
      }
    }
  }
}

// ---------------------------------------------------------------------------
// gemm8i v3: i8 dual-split GEMM, 256x128 tile, BK=64, 16x16x64 i8 MFMA.
// One phase per K-tile: reads+MFMA interleaved (compiler fine-grained lgkm),
// then lgkm0+barrier (WAR), stage t+2, vmcnt(6)+barrier (RAW, t+1 landed).
// Separate operand register sets (ah0/al0, ah1/al1) remove anti-deps so
// MFMA(qm0) can overlap the qm1 fragment reads. LDS 96KB -> 1 block/CU, so
// the extra ~32 VGPR are free. MFMA-per-acc order unchanged (i32 exact).
// EPI: 0 = f32 out, 2 = i8 h/l split out (re-quantized with INV_S_QK).
// ---------------------------------------------------------------------------
#define STG_I(DSTBASE, SH, SL, ROWBASE, KREAL)                                 \
  do {                                                                         \
    const i8* s0_ = (sc < 4 ? (SH) : (SL)) +                                   \
                    (size_t)((ROWBASE) + sr) * K + (KREAL) + ((sc & 3) << 4);  \
    const i8* s1_ = s0_ + (size_t)64 * K;                                      \
    __builtin_amdgcn_global_load_lds(AS1(s0_), AS3(&lds8[(DSTBASE) + ldsB]), 16, 0, 0); \
    __builtin_amdgcn_global_load_lds(AS1(s1_), AS3(&lds8[(DSTBASE) + 8192 + ldsB]), 16, 0, 0); \
  } while (0)

#define LDA_IV(BUF, QM, AH, AL)                                                \
  do {                                                                         \
    const int base_ = (BUF) * 49152;                                           \
    _Pragma("unroll") for (int i_ = 0; i_ < 4; ++i_) {                         \
      const int r_ = (QM) * 128 + wr * 64 + i_ * 16 + fr;                      \
      AH[i_] = *(const i32x4*)&lds8[base_ + r_ * 128 + ((ksl ^ (r_ & 7)) << 4)]; \
      AL[i_] = *(const i32x4*)&lds8[base_ + r_ * 128 + (((4 + ksl) ^ (r_ & 7)) << 4)]; \
    }                                                                          \
  } while (0)

#define LDB_IV(BUF)                                                            \
  do {                                                                         \
    const int base_ = (BUF) * 49152 + 32768;                                   \
    _Pragma("unroll") for (int j_ = 0; j_ < 2; ++j_) {                         \
      const int r_ = wc * 32 + (j_) * 16 + fr;                                 \
      bh[j_] = *(const i32x4*)&lds8[base_ + r_ * 128 + ((ksl ^ (r_ & 7)) << 4)]; \
      bl[j_] = *(const i32x4*)&lds8[base_ + r_ * 128 + (((4 + ksl) ^ (r_ & 7)) << 4)]; \
    }                                                                          \
  } while (0)

#define MMA_IV(QM, AH, AL)                                                     \
  do {                                                                         \
    _Pragma("unroll") for (int j_ = 0; j_ < 2; ++j_) {                         \
      _Pragma("unroll") for (int i_ = 0; i_ < 4; ++i_) {                       \
        accH[(QM) * 4 + i_][j_] = __builtin_amdgcn_mfma_i32_16x16x64_i8(       \
            AH[i_], bh[j_], accH[(QM) * 4 + i_][j_], 0, 0, 0);                 \
        accX[(QM) * 4 + i_][j_] = __builtin_amdgcn_mfma_i32_16x16x64_i8(       \
            AH[i_], bl[j_], accX[(QM) * 4 + i_][j_], 0, 0, 0);                 \
        accX[(QM) * 4 + i_][j_] = __builtin_amdgcn_mfma_i32_16x16x64_i8(       \
            AL[i_], bh[j_], accX[(QM) * 4 + i_][j_], 0, 0, 0);                 \
      }                                                                        \
    }                                                                          \
  } while (0)

template <int EPI>
__global__ __launch_bounds__(512, 2) void gemm8i(
    const i8* __restrict__ Ah, const i8* __restrict__ Al,
    const i8* __restrict__ Bh, const i8* __restrict__ Bl,
    const float* __restrict__ bias, float sAB, float* __restrict__ Cf,
    i8* __restrict__ Ch, i8* __restrict__ Cl, int M, int N, int K,
    long long sA, long long sB, long long sC) {
  extern __shared__ i8 lds8[];

  const int tt = threadIdx.x;
  const int lane = tt & 63;
  const int wv = tt >> 6;
  const int wr = wv >> 2;  // 0..1
  const int wc = wv & 3;   // 0..3
  const int fr = lane & 15;
  const int ksl = lane >> 4;  // 0..3

  const long long zb = blockIdx.z;
  const i8* pAh = Ah + zb * sA;
  const i8* pAl = Al + zb * sA;
  const i8* pBh = Bh + zb * sB;
  const i8* pBl = Bl + zb * sB;
  const int m0 = blockIdx.x * 256;
  const int n0 = blockIdx.y * 128;

  const int sr = tt >> 3;
  const int ss = tt & 7;
  const int sc = ss ^ (sr & 7);
  const int ldsB = (tt & ~63) * 16;

  i32x4 accH[8][2] = {};
  i32x4 accX[8][2] = {};
  i32x4 ah0[4], al0[4], ah1[4], al1[4], bh[2], bl[2];

  const int NT = K / 64;
  const int NITER = NT / 2;

  // prologue: t0 -> buf0 (6 loads), t1 -> buf1 (6 loads); drain t0.
  STG_I(0, pAh, pAl, m0, 0);
  STG_I(16384, pAh, pAl, m0 + 128, 0);
  STG_I(32768, pBh, pBl, n0, 0);
  STG_I(49152, pAh, pAl, m0, 64);
  STG_I(49152 + 16384, pAh, pAl, m0 + 128, 64);
  STG_I(49152 + 32768, pBh, pBl, n0, 64);
  asm volatile("s_waitcnt vmcnt(6)" ::: "memory");
  __builtin_amdgcn_s_barrier();

  for (int it = 0; it < NITER; ++it) {
    const int t0 = 2 * it;
    const int k2 = (t0 + 2 < NT ? t0 + 2 : NT - 1) * 64;
    const int k3 = (t0 + 3 < NT ? t0 + 3 : NT - 1) * 64;

    // ---- K-tile t0 (buf0): reads + MFMA overlap (no explicit lgkm wait) ----
    LDA_IV(0, 0, ah0, al0);
    LDB_IV(0);
    LDA_IV(0, 1, ah1, al1);
    MMA_IV(0, ah0, al0);
    MMA_IV(1, ah1, al1);
    asm volatile("s_waitcnt lgkmcnt(0)" ::: "memory");
    __builtin_amdgcn_s_barrier();          // all waves done reading buf0
    STG_I(0, pAh, pAl, m0, k2);            // t0+2 -> buf0
    STG_I(16384, pAh, pAl, m0 + 128, k2);
    STG_I(32768, pBh, pBl, n0, k2);
    asm volatile("s_waitcnt vmcnt(6)" ::: "memory");  // t0+1 landed
    __builtin_amdgcn_s_barrier();

    // ---- K-tile t0+1 (buf1) ----
    LDA_IV(1, 0, ah0, al0);
    LDB_IV(1);
    LDA_IV(1, 1, ah1, al1);
    MMA_IV(0, ah0, al0);
    MMA_IV(1, ah1, al1);
    asm volatile("s_waitcnt lgkmcnt(0)" ::: "memory");
    __builtin_amdgcn_s_barrier();
    STG_I(49152, pAh, pAl, m0, k3);        // t0+3 -> buf1
    STG_I(49152 + 16384, pAh, pAl, m0 + 128, k3);
    STG_I(49152 + 32768, pBh, pBl, n0, k3);
    asm volatile("s_waitcnt vmcnt(6)" ::: "memory");  // t0+2 landed
    __builtin_amdgcn_s_barrier();
  }

  // epilogue: C/D map col=lane&15, row=(lane>>4)*4+reg
  const int er = (lane >> 4) * 4;
  const int ec = lane & 15;
#pragma unroll
  for (int fi = 0; fi < 8; ++fi) {
    const int grow0 = m0 + (fi >> 2) * 128 + wr * 64 + (fi & 3) * 16 + er;
#pragma unroll
    for (int j = 0; j < 2; ++j) {
      const int gcol = n0 + wc * 32 + j * 16 + ec;
      const float bv = bias ? bias[gcol] : 0.0f;
#pragma unroll
      for (int r = 0; r < 4; ++r) {
        const float x =
            sAB * ((float)accH[fi][j][r] + (float)accX[fi][j][r] * 0.00390625f) + bv;
        const size_t off = (size_t)zb * sC + (size_t)(grow0 + r) * N + gcol;
        if constexpr (EPI == 0) {
          Cf[off] = x;  // f32 score (f16 failed: max|s|~176, ulp 0.125)
        } else {
          int2 qq = q8i(x, INV_S_QK);
          Ch[off] = (i8)qq.x;
          Cl[off] = (i8)qq.y;
        }
      }
    }
  }
}

// ---------------------------------------------------------------------------
// gemm8p v3: plain-bf16 256x128-tile, BK=64, one phase per K-tile with
// read/MFMA overlap (same scheme as gemm8i v3). Separate a0..a3 reg sets.
// ---------------------------------------------------------------------------
#define STG_P(DSTBASE, SRC, ROWBASE, KREAL)                                    \
  do {                                                                         \
    const u16* s0_ = (SRC) + (size_t)((ROWBASE) + sr) * K + (KREAL) + (sc << 3); \
    const u16* s1_ = s0_ + (size_t)64 * K;                                     \
    __builtin_amdgcn_global_load_lds(AS1(s0_), AS3(&lds[(DSTBASE) + ldsW]), 16, 0, 0); \
    __builtin_amdgcn_global_load_lds(AS1(s1_), AS3(&lds[(DSTBASE) + 4096 + ldsW]), 16, 0, 0); \
  } while (0)

#define LDA_P(BUF, QM, S, DST)                                                 \
  do {                                                                         \
    const int base_ = (BUF) * 24576 + (QM) * 8192;                             \
    _Pragma("unroll") for (int i_ = 0; i_ < 4; ++i_) {                         \
      const int r_ = wr * 64 + i_ * 16 + fr;                                   \
      DST[i_] = *(const bf16x8*)&lds[base_ + r_ * 64 + (((((S) * 4 + ksl)) ^ (r_ & 7)) << 3)]; \
    }                                                                          \
  } while (0)

#define LDB_P(BUF, S, DST)                                                     \
  do {                                                                         \
    const int base_ = (BUF) * 24576 + 16384;                                   \
    _Pragma("unroll") for (int j_ = 0; j_ < 2; ++j_) {                         \
      const int r_ = wc * 32 + j_ * 16 + fr;                                   \
      DST[j_] = *(const bf16x8*)&lds[base_ + r_ * 64 + (((((S) * 4 + ksl)) ^ (r_ & 7)) << 3)]; \
    }                                                                          \
  } while (0)

#define MMA_P(QM, A_, B_)                                                      \
  do {                                                                         \
    _Pragma("unroll") for (int i_ = 0; i_ < 4; ++i_) {                         \
      _Pragma("unroll") for (int j_ = 0; j_ < 2; ++j_) {                       \
        acc[(QM) * 4 + i_][j_] = __builtin_amdgcn_mfma_f32_16x16x32_bf16(      \
            A_[i_], B_[j_], acc[(QM) * 4 + i_][j_], 0, 0, 0);                  \
      }                                                                        \
    }                                                                          \
  } while (0)

template <int EPI>
__global__ __launch_bounds__(512, 2) void gemm8p(
    const u16* __restrict__ A, const u16* __restrict__ B,
    const float* __restrict__ bias, float* __restrict__ Cf,
    u16* __restrict__ Ch, int M, int N, int K,
    long long sA, long long sB, long long sC) {
  extern __shared__ u16 lds[];

  const int tt = threadIdx.x;
  const int lane = tt & 63;
  const int wv = tt >> 6;
  const int wr = wv >> 2;
  const int wc = wv & 3;
  const int fr = lane & 15;
  const int ksl = lane >> 4;

  const long long zb = blockIdx.z;
  const u16* pA = A + zb * sA;
  const u16* pB = B + zb * sB;
  const int m0 = blockIdx.x * 256;
  const int n0 = blockIdx.y * 128;

  const int sr = tt >> 3;
  const int ss = tt & 7;
  const int sc = ss ^ (sr & 7);
  const int ldsW = (tt & ~63) * 8;

  f32x4 acc[8][2] = {};
  bf16x8 a0[4], a1[4], a2[4], a3[4], b0[2], b1[2];

  const int NT = K / 64;

  // prologue: t0 -> buf0 (6 loads), t1 -> buf1 (6 loads); drain t0.
  STG_P(16384, pB, n0, 0);
  STG_P(0, pA, m0, 0);
  STG_P(8192, pA, m0 + 128, 0);
  STG_P(24576 + 16384, pB, n0, 64);
  STG_P(24576 + 0, pA, m0, 64);
  STG_P(24576 + 8192, pA, m0 + 128, 64);
  asm volatile("s_waitcnt vmcnt(6)" ::: "memory");
  __builtin_amdgcn_s_barrier();

  for (int it = 0; it < NT; ++it) {
    const int cur = it & 1;
    const int nb = cur * 24576;
    const int kf = (it + 2 < NT ? it + 2 : NT - 1) * 64;

    // reads + MFMA overlap (no explicit lgkm wait before MFMA)
    LDA_P(cur, 0, 0, a0);
    LDA_P(cur, 0, 1, a1);
    LDB_P(cur, 0, b0);
    LDB_P(cur, 1, b1);
    LDA_P(cur, 1, 0, a2);
    LDA_P(cur, 1, 1, a3);
    MMA_P(0, a0, b0);
    MMA_P(0, a1, b1);
    MMA_P(1, a2, b0);
    MMA_P(1, a3, b1);
    asm volatile("s_waitcnt lgkmcnt(0)" ::: "memory");
    __builtin_amdgcn_s_barrier();          // all waves done reading buf(cur)
    STG_P(nb + 16384, pB, n0, kf);         // t+2 -> buf(cur)
    STG_P(nb + 0, pA, m0, kf);
    STG_P(nb + 8192, pA, m0 + 128, kf);
    asm volatile("s_waitcnt vmcnt(6)" ::: "memory");  // t+1 landed
    __builtin_amdgcn_s_barrier();
  }

  const int er = (lane >> 4) * 4;
  const int ec = lane & 15;
#pragma unroll
  for (int fi = 0; fi < 8; ++fi) {
    const int qm = fi >> 2, i = fi & 3;
    const int grow0 = m0 + qm * 128 + wr * 64 + i * 16 + er;
#pragma unroll
    for (int j = 0; j < 2; ++j) {
      const int gcol = n0 + wc * 32 + j * 16 + ec;
      const float bv = bias ? bias[gcol] : 0.0f;
#pragma unroll
      for (int r = 0; r < 4; ++r) {
        const float x = acc[fi][j][r] + bv;
        const size_t off = (size_t)zb * sC + (size_t)(grow0 + r) * N + gcol;
        if constexpr (EPI == 0) Cf[off] = x;
        else Ch[off] = f2bf(x);
      }
    }
  }
}

// ---------------------------------------------------------------------------
// Row softmax over f32 scores, vectorized: in-place f32 weights + bf16 P.
// ---------------------------------------------------------------------------
__global__ __launch_bounds__(256) void softmax_rows_v(float* __restrict__ S,
                                                      u16* __restrict__ P) {
  const int T = 2048;
  const size_t row = blockIdx.x;
  float* sr = S + row * T;
  u16* prow = P + row * T;
  const int t = threadIdx.x;
  const int w = t >> 6, lane = t & 63;
  __shared__ float red[8];

  float4 r0 = ((const float4*)(sr + t * 8))[0];
  float4 r1 = ((const float4*)(sr + t * 8))[1];
  float v[8] = {r0.x, r0.y, r0.z, r0.w, r1.x, r1.y, r1.z, r1.w};
  float mx = -1e30f;
#pragma unroll
  for (int i = 0; i < 8; ++i) mx = fmaxf(mx, v[i]);
#pragma unroll
  for (int off = 32; off; off >>= 1) mx = fmaxf(mx, __shfl_xor(mx, off));
  if (lane == 0) red[w] = mx;
  __syncthreads();
  mx = fmaxf(fmaxf(red[0], red[1]), fmaxf(red[2], red[3]));

  float s = 0.f;
#pragma unroll
  for (int i = 0; i < 8; ++i) {
    v[i] = __expf(v[i] - mx);
    s += v[i];
  }
#pragma unroll
  for (int off = 32; off; off >>= 1) s += __shfl_xor(s, off);
  if (lane == 0) red[4 + w] = s;
  __syncthreads();
  s = (red[4] + red[5]) + (red[6] + red[7]);
  const float inv = 1.0f / s;

  u16x8 pv;
#pragma unroll
  for (int i = 0; i < 8; ++i) {
    v[i] *= inv;
    pv[i] = f2bf(v[i]);
  }
  float4* wr4 = (float4*)(sr + t * 8);
  wr4[0] = make_float4(v[0], v[1], v[2], v[3]);
  wr4[1] = make_float4(v[4], v[5], v[6], v[7]);
  ((u16x8*)prow)[t] = pv;
}

// ---------------------------------------------------------------------------
extern "C" void kernel_launch(void* const* d_in, const int* in_sizes, int n_in,
                              void* d_out, int out_size, void* d_ws,
                              size_t ws_size, hipStream_t stream) {
  (void)in_sizes; (void)n_in; (void)out_size; (void)ws_size;
  const float* query = (const float*)d_in[0];
  const float* key   = (const float*)d_in[1];
  const float* value = (const float*)d_in[2];
  const float* Wq    = (const float*)d_in[3];
  const float* bq    = (const float*)d_in[4];
  const float* Wo    = (const float*)d_in[5];
  const float* bo    = (const float*)d_in[6];

  const int S = 2048, D = 1024;
  const size_t n = (size_t)4 * S * D;   // 8,388,608 elements

  float* out = (float*)d_out;           // (B,S,D) f32, 32MB
  float* wts = out + n;                 // (B,S,T) f32 scores/weights, 64MB

  char* ws = (char*)d_ws;
  i8* wqt_h = (i8*)(ws);                     // 1MB  Wq^T hi (i8)
  i8* wqt_l = (i8*)(ws + (1ull << 20));      // 1MB  Wq^T lo
  u16* wot  = (u16*)(ws + (2ull << 20));     // 2MB  Wo^T bf16
  u16* wq_b = (u16*)(ws + (4ull << 20));     // 2MB  Wq bf16
  u16* wqoT = (u16*)(ws + (6ull << 20));     // 2MB  (Wq@Wo)^T bf16
  float* bqo = (float*)(ws + (8ull << 20));  // 4KB
  i8* QKh = (i8*)(ws + (9ull << 20));        // 16MB  [Q;K] hi
  i8* QKl = (i8*)(ws + (25ull << 20));       // 16MB  [Q;K] lo
  u16* tmp = (u16*)(ws + (41ull << 20));     // 16MB  P@value^T (total ws 57MB)
  u16* P = (u16*)(ws + (9ull << 20));        // 32MB overlay QKh+QKl (dead)

  // scratch in d_out: wts region holds input splits until score GEMM writes;
  // out region holds value^T until the final GEMM writes.
  i8* ah = (i8*)wts;        // [q;k] hi, 16MB (dead after proj GEMM)
  i8* al = ah + 2 * n;      // [q;k] lo, 16MB
  u16* valT = (u16*)out;    // (B, D, T) bf16, 16MB (dead after PV)

  hipFuncSetAttribute((const void*)&gemm8i<2>,
                      hipFuncAttributeMaxDynamicSharedMemorySize, 98304);
  hipFuncSetAttribute((const void*)&gemm8i<0>,
                      hipFuncAttributeMaxDynamicSharedMemorySize, 98304);
  hipFuncSetAttribute((const void*)&gemm8p<1>,
                      hipFuncAttributeMaxDynamicSharedMemorySize, 98304);
  hipFuncSetAttribute((const void*)&gemm8p<0>,
                      hipFuncAttributeMaxDynamicSharedMemorySize, 98304);

  // 1. fused prep: value^T + split q,k + weight prep (11264 blocks)
  prep_all<<<11264, 256, 0, stream>>>(query, key, value, Wq, Wo, ah, al,
                                      ah + n, al + n, valT, wqt_h, wqt_l, wot,
                                      wq_b);
  // 2. WqoT = (Wq@Wo)^T bf16
  gemm_bt<1><<<dim3(8, 8, 1), 256, 0, stream>>>(
      wot, wq_b, nullptr, nullptr, wqoT, 1024, 1024, 1024, 0, 0, 0);
  // 3. bqo = bq@Wo + bo
  bqo_kernel<<<256, 256, 0, stream>>>(bq, wot, bo, bqo, D);
  // 4. [Q;K] = [q;k] @ Wq + bq  (i8 dual-split GEMM, i8 split out)
  gemm8i<2><<<dim3(64, 8, 1), 512, 98304, stream>>>(
      ah, al, wqt_h, wqt_l, bq, S_IN * S_W, nullptr, QKh, QKl,
      16384, 1024, 1024, 0, 0, 0);
  // 5. score = Q @ K^T (i8 dual-split GEMM, f32 out into weights region)
  gemm8i<0><<<dim3(8, 16, 4), 512, 98304, stream>>>(
      QKh, QKl, QKh + n, QKl + n, nullptr, S_QK * S_QK, wts, nullptr, nullptr,
      2048, 2048, 1024, (long long)S * D, (long long)S * D, (long long)S * S);
  // 6. softmax rows (in-place, vectorized) + bf16 P
  softmax_rows_v<<<8192, 256, 0, stream>>>(wts, P);
  // 7. tmp = P @ value^T — gemm8p
  gemm8p<1><<<dim3(8, 8, 4), 512, 98304, stream>>>(
      P, valT, nullptr, nullptr, tmp, 2048, 1024, 2048, (long long)S * S,
      (long long)D * S, (long long)S * D);
  // 8. out = tmp @ Wqo + bqo — gemm8p
  gemm8p<0><<<dim3(32, 8, 1), 512, 98304, stream>>>(
      tmp, wqoT, bqo, out, nullptr, 8192, 1024, 1024, 0, 0, 0);
}

// Round 13
// 272.437 us; speedup vs baseline: 1.0094x; 1.0094x over previous
//
#include <hip/hip_runtime.h>

typedef unsigned short u16;
typedef unsigned int u32;
typedef signed char i8;
typedef __bf16 bf16x8 __attribute__((ext_vector_type(8)));
typedef float f32x4 __attribute__((ext_vector_type(4)));
typedef int i32x4 __attribute__((ext_vector_type(4)));
typedef i8 i8x4 __attribute__((ext_vector_type(4)));
typedef u16 u16x8 __attribute__((ext_vector_type(8)));

#define AS1(p) ((const __attribute__((address_space(1))) void*)(p))
#define AS3(p) ((__attribute__((address_space(3))) void*)(p))

__device__ __forceinline__ u16 f2bf(float x) {
  u32 u = __float_as_uint(x);
  u32 r = u + 0x7fffu + ((u >> 16) & 1u);
  return (u16)(r >> 16);
}
__device__ __forceinline__ float bf2f(u16 h) {
  return __uint_as_float(((u32)h) << 16);
}

// ---------------------------------------------------------------------------
// i8 dual-split quantizer: x ~= s*(h + l/256), |err| <= s/512.
// ---------------------------------------------------------------------------
#define S_IN (8.0f / 127.0f)
#define S_W (0.25f / 127.0f)
#define S_QK (8.0f / 127.0f)
#define INV_S_IN (127.0f / 8.0f)
#define INV_S_W (508.0f)
#define INV_S_QK (127.0f / 8.0f)

__device__ __forceinline__ int2 q8i(float x, float inv_s) {
  float t = fminf(fmaxf(x * inv_s, -126.99f), 126.99f);
  float hf = rintf(t);
  float lf = fminf(fmaxf(rintf((t - hf) * 256.0f), -127.0f), 127.0f);
  return make_int2((int)hf, (int)lf);
}

// ---------------------------------------------------------------------------
// prep_all: one launch fusing three independent preprocessing stages.
// ---------------------------------------------------------------------------
__global__ __launch_bounds__(256) void prep_all(
    const float* __restrict__ q, const float* __restrict__ k,
    const float* __restrict__ value, const float* __restrict__ Wq,
    const float* __restrict__ Wo, i8* __restrict__ qh, i8* __restrict__ ql,
    i8* __restrict__ kh, i8* __restrict__ kl, u16* __restrict__ valT,
    i8* __restrict__ wqt_h, i8* __restrict__ wqt_l, u16* __restrict__ wot,
    u16* __restrict__ wq_b) {
  __shared__ float tileA[32][33];
  __shared__ float tileB[32][33];
  const int bid = blockIdx.x;
  const int tid = threadIdx.x;
  const int D = 1024;

  if (bid < 8192) {
    const int bx = bid & 31;
    const int by = (bid >> 5) & 63;
    const int bz = bid >> 11;
    const int tx = tid & 31, ty = tid >> 5;
    const int c0 = bx * 32, r0 = by * 32;
    const size_t zi = (size_t)bz * 2048 * 1024;
#pragma unroll
    for (int i = ty; i < 32; i += 8)
      tileA[i][tx] = value[zi + (size_t)(r0 + i) * D + (c0 + tx)];
    __syncthreads();
#pragma unroll
    for (int i = ty; i < 32; i += 8)
      valT[zi + (size_t)(c0 + i) * 2048 + (r0 + tx)] = f2bf(tileA[tx][i]);
  } else if (bid < 10240) {
    const int b2 = bid - 8192;
    const int n4 = 2097152;
    const int stride = 2048 * 256;
    for (int i = b2 * 256 + tid; i < n4; i += stride) {
      float4 x = ((const float4*)q)[i];
      float xs[4] = {x.x, x.y, x.z, x.w};
      i8x4 h, l;
#pragma unroll
      for (int e = 0; e < 4; ++e) {
        int2 r = q8i(xs[e], INV_S_IN);
        h[e] = (i8)r.x;
        l[e] = (i8)r.y;
      }
      ((i8x4*)qh)[i] = h;
      ((i8x4*)ql)[i] = l;
      x = ((const float4*)k)[i];
      float ys[4] = {x.x, x.y, x.z, x.w};
#pragma unroll
      for (int e = 0; e < 4; ++e) {
        int2 r = q8i(ys[e], INV_S_IN);
        h[e] = (i8)r.x;
        l[e] = (i8)r.y;
      }
      ((i8x4*)kh)[i] = h;
      ((i8x4*)kl)[i] = l;
    }
  } else {
    const int r = bid - 10240;
    const int bx = r & 31, by = r >> 5;
    const int tx = tid & 31, ty = tid >> 5;
    const int c0 = bx * 32, r0 = by * 32;
#pragma unroll
    for (int i = ty; i < 32; i += 8) {
      float xq = Wq[(size_t)(r0 + i) * D + c0 + tx];
      tileA[i][tx] = xq;
      wq_b[(size_t)(r0 + i) * D + c0 + tx] = f2bf(xq);
      tileB[i][tx] = Wo[(size_t)(r0 + i) * D + c0 + tx];
    }
    __syncthreads();
#pragma unroll
    for (int i = ty; i < 32; i += 8) {
      float x = tileA[tx][i];
      int2 rr = q8i(x, INV_S_W);
      size_t o = (size_t)(c0 + i) * D + r0 + tx;
      wqt_h[o] = (i8)rr.x;
      wqt_l[o] = (i8)rr.y;
      wot[o] = f2bf(tileB[tx][i]);
    }
  }
}

// bqo[f] = sum_e bq[e]*Wo[e][f] + bo[f]   via wot (Wo^T bf16).
__global__ __launch_bounds__(256) void bqo_kernel(const float* __restrict__ bq,
                                                  const u16* __restrict__ wot,
                                                  const float* __restrict__ bo,
                                                  float* __restrict__ bqo,
                                                  int D) {
  const int f = blockIdx.x * 4 + (threadIdx.x >> 6);
  const int lane = threadIdx.x & 63;
  const u16* wr_ = wot + (size_t)f * D;
  float s = 0.f;
  for (int e = lane; e < D; e += 64) s += bq[e] * bf2f(wr_[e]);
#pragma unroll
  for (int off = 32; off; off >>= 1) s += __shfl_xor(s, off);
  if (lane == 0) bqo[f] = s + bo[f];
}

// ---------------------------------------------------------------------------
// 128x128 2-barrier GEMM (only for the tiny Wqo GEMM).
// ---------------------------------------------------------------------------
template <int EPI>
__global__ __launch_bounds__(256, 2) void gemm_bt(
    const u16* __restrict__ Ah, const u16* __restrict__ Bh,
    const float* __restrict__ bias, float* __restrict__ Cf,
    u16* __restrict__ Ch, int M, int N, int K,
    long long sA, long long sB, long long sC) {
  __shared__ alignas(16) u16 As[128 * 32];
  __shared__ alignas(16) u16 Bs[128 * 32];

  const int t = threadIdx.x;
  const int lane = t & 63;
  const int w = t >> 6;
  const int wr = w >> 1, wc = w & 1;

  const long long zb = blockIdx.z;
  const u16* pA = Ah + zb * sA;
  const u16* pB = Bh + zb * sB;

  const int m0 = blockIdx.x * 128;
  const int n0 = blockIdx.y * 128;

  f32x4 acc[4][4] = {};

  const int row0 = t >> 2;
  const int colS = (t & 3) * 8;
  const int lds0 = (t & ~63) * 8;
  const int lds1 = (256 + (t & ~63)) * 8;

  const size_t aoff0 = (size_t)(m0 + row0) * K + colS;
  const size_t aoff1 = (size_t)(m0 + row0 + 64) * K + colS;
  const size_t boff0 = (size_t)(n0 + row0) * K + colS;
  const size_t boff1 = (size_t)(n0 + row0 + 64) * K + colS;

  for (int k0 = 0; k0 < K; k0 += 32) {
    __syncthreads();
    __builtin_amdgcn_global_load_lds(AS1(pA + aoff0 + k0), AS3(&As[lds0]), 16, 0, 0);
    __builtin_amdgcn_global_load_lds(AS1(pA + aoff1 + k0), AS3(&As[lds1]), 16, 0, 0);
    __builtin_amdgcn_global_load_lds(AS1(pB + boff0 + k0), AS3(&Bs[lds0]), 16, 0, 0);
    __builtin_amdgcn_global_load_lds(AS1(pB + boff1 + k0), AS3(&Bs[lds1]), 16, 0, 0);
    __syncthreads();

    const int fr = lane & 15;
    const int kc = (lane >> 4) * 8;
    bf16x8 a[4], b[4];
#pragma unroll
    for (int i = 0; i < 4; ++i)
      a[i] = *(const bf16x8*)&As[(wr * 64 + i * 16 + fr) * 32 + kc];
#pragma unroll
    for (int j = 0; j < 4; ++j)
      b[j] = *(const bf16x8*)&Bs[(wc * 64 + j * 16 + fr) * 32 + kc];
#pragma unroll
    for (int i = 0; i < 4; ++i)
#pragma unroll
      for (int j = 0; j < 4; ++j)
        acc[i][j] = __builtin_amdgcn_mfma_f32_16x16x32_bf16(a[i], b[j], acc[i][j], 0, 0, 0);
  }

  const int er = (lane >> 4) * 4;
  const int ec = lane & 15;
#pragma unroll
  for (int j = 0; j < 4; ++j) {
    const int gcol = n0 + wc * 64 + j * 16 + ec;
    const float bv = bias ? bias[gcol] : 0.0f;
#pragma unroll
    for (int i = 0; i < 4; ++i) {
      const int grow0 = m0 + wr * 64 + i * 16 + er;
#pragma unroll
      for (int r = 0; r < 4; ++r) {
        const float x = acc[i][j][r] + bv;
        const size_t off = (size_t)zb * sC + (size_t)(grow0 + r) * N + gcol;
        if constexpr (EPI == 0) Cf[off] = x;
        else Ch[off] = f2bf(x);
      }
    }
  }
}

// ---------------------------------------------------------------------------
// gemm8i v4: i8 dual-split GEMM, 256x128 tile, BK=64, 16x16x64 i8 MFMA.
// Wave grid flipped to 4M x 2N (per-wave 64x64 output) to cut LDS-read
// redundancy: A read 2x (was 4x), B 4x of half-size (was 2x) -> 128KB/K-tile
// (was 160KB). Same LDS layout/staging/swizzle; same per-element K order
// (i32 exact). One phase per K-tile with read/MFMA overlap (round 11).
// EPI: 0 = f32 out, 2 = i8 h/l split out (re-quantized with INV_S_QK).
// ---------------------------------------------------------------------------
#define STG_I(DSTBASE, SH, SL, ROWBASE, KREAL)                                 \
  do {                                                                         \
    const i8* s0_ = (sc < 4 ? (SH) : (SL)) +                                   \
                    (size_t)((ROWBASE) + sr) * K + (KREAL) + ((sc & 3) << 4);  \
    const i8* s1_ = s0_ + (size_t)64 * K;                                      \
    __builtin_amdgcn_global_load_lds(AS1(s0_), AS3(&lds8[(DSTBASE) + ldsB]), 16, 0, 0); \
    __builtin_amdgcn_global_load_lds(AS1(s1_), AS3(&lds8[(DSTBASE) + 8192 + ldsB]), 16, 0, 0); \
  } while (0)

// A frags: rows wr*64 + i*16 + fr (wr 0..3), 4 frags x (h,l)
#define LDA_IV(BUF)                                                            \
  do {                                                                         \
    const int base_ = (BUF) * 49152;                                           \
    _Pragma("unroll") for (int i_ = 0; i_ < 4; ++i_) {                         \
      const int r_ = wr * 64 + i_ * 16 + fr;                                   \
      ah[i_] = *(const i32x4*)&lds8[base_ + r_ * 128 + ((ksl ^ (r_ & 7)) << 4)]; \
      al[i_] = *(const i32x4*)&lds8[base_ + r_ * 128 + (((4 + ksl) ^ (r_ & 7)) << 4)]; \
    }                                                                          \
  } while (0)

// B frags: cols wc*64 + j*16 + fr (wc 0..1), 4 frags x (h,l)
#define LDB_IV(BUF)                                                            \
  do {                                                                         \
    const int base_ = (BUF) * 49152 + 32768;                                   \
    _Pragma("unroll") for (int j_ = 0; j_ < 4; ++j_) {                         \
      const int r_ = wc * 64 + j_ * 16 + fr;                                   \
      bh[j_] = *(const i32x4*)&lds8[base_ + r_ * 128 + ((ksl ^ (r_ & 7)) << 4)]; \
      bl[j_] = *(const i32x4*)&lds8[base_ + r_ * 128 + (((4 + ksl) ^ (r_ & 7)) << 4)]; \
    }                                                                          \
  } while (0)

#define MMA_IV()                                                               \
  do {                                                                         \
    _Pragma("unroll") for (int j_ = 0; j_ < 4; ++j_) {                         \
      _Pragma("unroll") for (int i_ = 0; i_ < 4; ++i_) {                       \
        accH[i_][j_] = __builtin_amdgcn_mfma_i32_16x16x64_i8(                  \
            ah[i_], bh[j_], accH[i_][j_], 0, 0, 0);                            \
        accX[i_][j_] = __builtin_amdgcn_mfma_i32_16x16x64_i8(                  \
            ah[i_], bl[j_], accX[i_][j_], 0, 0, 0);                            \
        accX[i_][j_] = __builtin_amdgcn_mfma_i32_16x16x64_i8(                  \
            al[i_], bh[j_], accX[i_][j_], 0, 0, 0);                            \
      }                                                                        \
    }                                                                          \
  } while (0)

template <int EPI>
__global__ __launch_bounds__(512, 2) void gemm8i(
    const i8* __restrict__ Ah, const i8* __restrict__ Al,
    const i8* __restrict__ Bh, const i8* __restrict__ Bl,
    const float* __restrict__ bias, float sAB, float* __restrict__ Cf,
    i8* __restrict__ Ch, i8* __restrict__ Cl, int M, int N, int K,
    long long sA, long long sB, long long sC) {
  extern __shared__ i8 lds8[];

  const int tt = threadIdx.x;
  const int lane = tt & 63;
  const int wv = tt >> 6;
  const int wr = wv >> 1;  // 0..3 (M-group of 64 rows)
  const int wc = wv & 1;   // 0..1 (N-group of 64 cols)
  const int fr = lane & 15;
  const int ksl = lane >> 4;  // 0..3

  const long long zb = blockIdx.z;
  const i8* pAh = Ah + zb * sA;
  const i8* pAl = Al + zb * sA;
  const i8* pBh = Bh + zb * sB;
  const i8* pBl = Bl + zb * sB;
  const int m0 = blockIdx.x * 256;
  const int n0 = blockIdx.y * 128;

  const int sr = tt >> 3;
  const int ss = tt & 7;
  const int sc = ss ^ (sr & 7);
  const int ldsB = (tt & ~63) * 16;

  i32x4 accH[4][4] = {};
  i32x4 accX[4][4] = {};
  i32x4 ah[4], al[4], bh[4], bl[4];

  const int NT = K / 64;
  const int NITER = NT / 2;

  // prologue: t0 -> buf0 (6 loads), t1 -> buf1 (6 loads); drain t0.
  STG_I(0, pAh, pAl, m0, 0);
  STG_I(16384, pAh, pAl, m0 + 128, 0);
  STG_I(32768, pBh, pBl, n0, 0);
  STG_I(49152, pAh, pAl, m0, 64);
  STG_I(49152 + 16384, pAh, pAl, m0 + 128, 64);
  STG_I(49152 + 32768, pBh, pBl, n0, 64);
  asm volatile("s_waitcnt vmcnt(6)" ::: "memory");
  __builtin_amdgcn_s_barrier();

  for (int it = 0; it < NITER; ++it) {
    const int t0 = 2 * it;
    const int k2 = (t0 + 2 < NT ? t0 + 2 : NT - 1) * 64;
    const int k3 = (t0 + 3 < NT ? t0 + 3 : NT - 1) * 64;

    // ---- K-tile t0 (buf0) ----
    LDA_IV(0);
    LDB_IV(0);
    MMA_IV();
    asm volatile("s_waitcnt lgkmcnt(0)" ::: "memory");
    __builtin_amdgcn_s_barrier();          // all waves done reading buf0
    STG_I(0, pAh, pAl, m0, k2);            // t0+2 -> buf0
    STG_I(16384, pAh, pAl, m0 + 128, k2);
    STG_I(32768, pBh, pBl, n0, k2);
    asm volatile("s_waitcnt vmcnt(6)" ::: "memory");  // t0+1 landed
    __builtin_amdgcn_s_barrier();

    // ---- K-tile t0+1 (buf1) ----
    LDA_IV(1);
    LDB_IV(1);
    MMA_IV();
    asm volatile("s_waitcnt lgkmcnt(0)" ::: "memory");
    __builtin_amdgcn_s_barrier();
    STG_I(49152, pAh, pAl, m0, k3);        // t0+3 -> buf1
    STG_I(49152 + 16384, pAh, pAl, m0 + 128, k3);
    STG_I(49152 + 32768, pBh, pBl, n0, k3);
    asm volatile("s_waitcnt vmcnt(6)" ::: "memory");  // t0+2 landed
    __builtin_amdgcn_s_barrier();
  }

  // epilogue: C/D map col=lane&15, row=(lane>>4)*4+reg
  const int er = (lane >> 4) * 4;
  const int ec = lane & 15;
#pragma unroll
  for (int i = 0; i < 4; ++i) {
    const int grow0 = m0 + wr * 64 + i * 16 + er;
#pragma unroll
    for (int j = 0; j < 4; ++j) {
      const int gcol = n0 + wc * 64 + j * 16 + ec;
      const float bv = bias ? bias[gcol] : 0.0f;
#pragma unroll
      for (int r = 0; r < 4; ++r) {
        const float x =
            sAB * ((float)accH[i][j][r] + (float)accX[i][j][r] * 0.00390625f) + bv;
        const size_t off = (size_t)zb * sC + (size_t)(grow0 + r) * N + gcol;
        if constexpr (EPI == 0) {
          Cf[off] = x;  // f32 score (f16 failed: max|s|~176, ulp 0.125)
        } else {
          int2 qq = q8i(x, INV_S_QK);
          Ch[off] = (i8)qq.x;
          Cl[off] = (i8)qq.y;
        }
      }
    }
  }
}

// ---------------------------------------------------------------------------
// gemm8p v4: plain-bf16 256x128-tile, BK=64, wave grid 4M x 2N (64x64/wave),
// one phase per K-tile with read/MFMA overlap. LDS reads -20% vs v3.
// ---------------------------------------------------------------------------
#define STG_P(DSTBASE, SRC, ROWBASE, KREAL)                                    \
  do {                                                                         \
    const u16* s0_ = (SRC) + (size_t)((ROWBASE) + sr) * K + (KREAL) + (sc << 3); \
    const u16* s1_ = s0_ + (size_t)64 * K;                                     \
    __builtin_amdgcn_global_load_lds(AS1(s0_), AS3(&lds[(DSTBASE) + ldsW]), 16, 0, 0); \
    __builtin_amdgcn_global_load_lds(AS1(s1_), AS3(&lds[(DSTBASE) + 4096 + ldsW]), 16, 0, 0); \
  } while (0)

// A frags: rows wr*64 + i*16 + fr, K-step S; contiguous A rows 0..255
#define LDA_P(BUF, S, DST)                                                     \
  do {                                                                         \
    const int base_ = (BUF) * 24576;                                           \
    _Pragma("unroll") for (int i_ = 0; i_ < 4; ++i_) {                         \
      const int r_ = wr * 64 + i_ * 16 + fr;                                   \
      DST[i_] = *(const bf16x8*)&lds[base_ + r_ * 64 + (((((S) * 4 + ksl)) ^ (r_ & 7)) << 3)]; \
    }                                                                          \
  } while (0)

// B frags: cols wc*64 + j*16 + fr, K-step S
#define LDB_P(BUF, S, DST)                                                     \
  do {                                                                         \
    const int base_ = (BUF) * 24576 + 16384;                                   \
    _Pragma("unroll") for (int j_ = 0; j_ < 4; ++j_) {                         \
      const int r_ = wc * 64 + j_ * 16 + fr;                                   \
      DST[j_] = *(const bf16x8*)&lds[base_ + r_ * 64 + (((((S) * 4 + ksl)) ^ (r_ & 7)) << 3)]; \
    }                                                                          \
  } while (0)

#define MMA_P(A_, B_)                                                          \
  do {                                                                         \
    _Pragma("unroll") for (int i_ = 0; i_ < 4; ++i_) {                         \
      _Pragma("unroll") for (int j_ = 0; j_ < 4; ++j_) {                       \
        acc[i_][j_] = __builtin_amdgcn_mfma_f32_16x16x32_bf16(                 \
            A_[i_], B_[j_], acc[i_][j_], 0, 0, 0);                             \
      }                                                                        \
    }                                                                          \
  } while (0)

template <int EPI>
__global__ __launch_bounds__(512, 2) void gemm8p(
    const u16* __restrict__ A, const u16* __restrict__ B,
    const float* __restrict__ bias, float* __restrict__ Cf,
    u16* __restrict__ Ch, int M, int N, int K,
    long long sA, long long sB, long long sC) {
  extern __shared__ u16 lds[];

  const int tt = threadIdx.x;
  const int lane = tt & 63;
  const int wv = tt >> 6;
  const int wr = wv >> 1;  // 0..3
  const int wc = wv & 1;   // 0..1
  const int fr = lane & 15;
  const int ksl = lane >> 4;

  const long long zb = blockIdx.z;
  const u16* pA = A + zb * sA;
  const u16* pB = B + zb * sB;
  const int m0 = blockIdx.x * 256;
  const int n0 = blockIdx.y * 128;

  const int sr = tt >> 3;
  const int ss = tt & 7;
  const int sc = ss ^ (sr & 7);
  const int ldsW = (tt & ~63) * 8;

  f32x4 acc[4][4] = {};
  bf16x8 a0[4], a1[4], b0[4], b1[4];

  const int NT = K / 64;

  // prologue: t0 -> buf0 (6 loads), t1 -> buf1 (6 loads); drain t0.
  STG_P(16384, pB, n0, 0);
  STG_P(0, pA, m0, 0);
  STG_P(8192, pA, m0 + 128, 0);
  STG_P(24576 + 16384, pB, n0, 64);
  STG_P(24576 + 0, pA, m0, 64);
  STG_P(24576 + 8192, pA, m0 + 128, 64);
  asm volatile("s_waitcnt vmcnt(6)" ::: "memory");
  __builtin_amdgcn_s_barrier();

  for (int it = 0; it < NT; ++it) {
    const int cur = it & 1;
    const int nb = cur * 24576;
    const int kf = (it + 2 < NT ? it + 2 : NT - 1) * 64;

    // reads + MFMA overlap; K-steps in ascending order per element
    LDA_P(cur, 0, a0);
    LDB_P(cur, 0, b0);
    LDA_P(cur, 1, a1);
    LDB_P(cur, 1, b1);
    MMA_P(a0, b0);
    MMA_P(a1, b1);
    asm volatile("s_waitcnt lgkmcnt(0)" ::: "memory");
    __builtin_amdgcn_s_barrier();          // all waves done reading buf(cur)
    STG_P(nb + 16384, pB, n0, kf);         // t+2 -> buf(cur)
    STG_P(nb + 0, pA, m0, kf);
    STG_P(nb + 8192, pA, m0 + 128, kf);
    asm volatile("s_waitcnt vmcnt(6)" ::: "memory");  // t+1 landed
    __builtin_amdgcn_s_barrier();
  }

  const int er = (lane >> 4) * 4;
  const int ec = lane & 15;
#pragma unroll
  for (int i = 0; i < 4; ++i) {
    const int grow0 = m0 + wr * 64 + i * 16 + er;
#pragma unroll
    for (int j = 0; j < 4; ++j) {
      const int gcol = n0 + wc * 64 + j * 16 + ec;
      const float bv = bias ? bias[gcol] : 0.0f;
#pragma unroll
      for (int r = 0; r < 4; ++r) {
        const float x = acc[i][j][r] + bv;
        const size_t off = (size_t)zb * sC + (size_t)(grow0 + r) * N + gcol;
        if constexpr (EPI == 0) Cf[off] = x;
        else Ch[off] = f2bf(x);
      }
    }
  }
}

// ---------------------------------------------------------------------------
// Row softmax over f32 scores, vectorized: in-place f32 weights + bf16 P.
// ---------------------------------------------------------------------------
__global__ __launch_bounds__(256) void softmax_rows_v(float* __restrict__ S,
                                                      u16* __restrict__ P) {
  const int T = 2048;
  const size_t row = blockIdx.x;
  float* sr = S + row * T;
  u16* prow = P + row * T;
  const int t = threadIdx.x;
  const int w = t >> 6, lane = t & 63;
  __shared__ float red[8];

  float4 r0 = ((const float4*)(sr + t * 8))[0];
  float4 r1 = ((const float4*)(sr + t * 8))[1];
  float v[8] = {r0.x, r0.y, r0.z, r0.w, r1.x, r1.y, r1.z, r1.w};
  float mx = -1e30f;
#pragma unroll
  for (int i = 0; i < 8; ++i) mx = fmaxf(mx, v[i]);
#pragma unroll
  for (int off = 32; off; off >>= 1) mx = fmaxf(mx, __shfl_xor(mx, off));
  if (lane == 0) red[w] = mx;
  __syncthreads();
  mx = fmaxf(fmaxf(red[0], red[1]), fmaxf(red[2], red[3]));

  float s = 0.f;
#pragma unroll
  for (int i = 0; i < 8; ++i) {
    v[i] = __expf(v[i] - mx);
    s += v[i];
  }
#pragma unroll
  for (int off = 32; off; off >>= 1) s += __shfl_xor(s, off);
  if (lane == 0) red[4 + w] = s;
  __syncthreads();
  s = (red[4] + red[5]) + (red[6] + red[7]);
  const float inv = 1.0f / s;

  u16x8 pv;
#pragma unroll
  for (int i = 0; i < 8; ++i) {
    v[i] *= inv;
    pv[i] = f2bf(v[i]);
  }
  float4* wr4 = (float4*)(sr + t * 8);
  wr4[0] = make_float4(v[0], v[1], v[2], v[3]);
  wr4[1] = make_float4(v[4], v[5], v[6], v[7]);
  ((u16x8*)prow)[t] = pv;
}

// ---------------------------------------------------------------------------
extern "C" void kernel_launch(void* const* d_in, const int* in_sizes, int n_in,
                              void* d_out, int out_size, void* d_ws,
                              size_t ws_size, hipStream_t stream) {
  (void)in_sizes; (void)n_in; (void)out_size; (void)ws_size;
  const float* query = (const float*)d_in[0];
  const float* key   = (const float*)d_in[1];
  const float* value = (const float*)d_in[2];
  const float* Wq    = (const float*)d_in[3];
  const float* bq    = (const float*)d_in[4];
  const float* Wo    = (const float*)d_in[5];
  const float* bo    = (const float*)d_in[6];

  const int S = 2048, D = 1024;
  const size_t n = (size_t)4 * S * D;   // 8,388,608 elements

  float* out = (float*)d_out;           // (B,S,D) f32, 32MB
  float* wts = out + n;                 // (B,S,T) f32 scores/weights, 64MB

  char* ws = (char*)d_ws;
  i8* wqt_h = (i8*)(ws);                     // 1MB  Wq^T hi (i8)
  i8* wqt_l = (i8*)(ws + (1ull << 20));      // 1MB  Wq^T lo
  u16* wot  = (u16*)(ws + (2ull << 20));     // 2MB  Wo^T bf16
  u16* wq_b = (u16*)(ws + (4ull << 20));     // 2MB  Wq bf16
  u16* wqoT = (u16*)(ws + (6ull << 20));     // 2MB  (Wq@Wo)^T bf16
  float* bqo = (float*)(ws + (8ull << 20));  // 4KB
  i8* QKh = (i8*)(ws + (9ull << 20));        // 16MB  [Q;K] hi
  i8* QKl = (i8*)(ws + (25ull << 20));       // 16MB  [Q;K] lo
  u16* tmp = (u16*)(ws + (41ull << 20));     // 16MB  P@value^T (total ws 57MB)
  u16* P = (u16*)(ws + (9ull << 20));        // 32MB overlay QKh+QKl (dead)

  // scratch in d_out: wts region holds input splits until score GEMM writes;
  // out region holds value^T until the final GEMM writes.
  i8* ah = (i8*)wts;        // [q;k] hi, 16MB (dead after proj GEMM)
  i8* al = ah + 2 * n;      // [q;k] lo, 16MB
  u16* valT = (u16*)out;    // (B, D, T) bf16, 16MB (dead after PV)

  hipFuncSetAttribute((const void*)&gemm8i<2>,
                      hipFuncAttributeMaxDynamicSharedMemorySize, 98304);
  hipFuncSetAttribute((const void*)&gemm8i<0>,
                      hipFuncAttributeMaxDynamicSharedMemorySize, 98304);
  hipFuncSetAttribute((const void*)&gemm8p<1>,
                      hipFuncAttributeMaxDynamicSharedMemorySize, 98304);
  hipFuncSetAttribute((const void*)&gemm8p<0>,
                      hipFuncAttributeMaxDynamicSharedMemorySize, 98304);

  // 1. fused prep: value^T + split q,k + weight prep (11264 blocks)
  prep_all<<<11264, 256, 0, stream>>>(query, key, value, Wq, Wo, ah, al,
                                      ah + n, al + n, valT, wqt_h, wqt_l, wot,
                                      wq_b);
  // 2. WqoT = (Wq@Wo)^T bf16
  gemm_bt<1><<<dim3(8, 8, 1), 256, 0, stream>>>(
      wot, wq_b, nullptr, nullptr, wqoT, 1024, 1024, 1024, 0, 0, 0);
  // 3. bqo = bq@Wo + bo
  bqo_kernel<<<256, 256, 0, stream>>>(bq, wot, bo, bqo, D);
  // 4. [Q;K] = [q;k] @ Wq + bq  (i8 dual-split GEMM, i8 split out)
  gemm8i<2><<<dim3(64, 8, 1), 512, 98304, stream>>>(
      ah, al, wqt_h, wqt_l, bq, S_IN * S_W, nullptr, QKh, QKl,
      16384, 1024, 1024, 0, 0, 0);
  // 5. score = Q @ K^T (i8 dual-split GEMM, f32 out into weights region)
  gemm8i<0><<<dim3(8, 16, 4), 512, 98304, stream>>>(
      QKh, QKl, QKh + n, QKl + n, nullptr, S_QK * S_QK, wts, nullptr, nullptr,
      2048, 2048, 1024, (long long)S * D, (long long)S * D, (long long)S * S);
  // 6. softmax rows (in-place, vectorized) + bf16 P
  softmax_rows_v<<<8192, 256, 0, stream>>>(wts, P);
  // 7. tmp = P @ value^T — gemm8p
  gemm8p<1><<<dim3(8, 8, 4), 512, 98304, stream>>>(
      P, valT, nullptr, nullptr, tmp, 2048, 1024, 2048, (long long)S * S,
      (long long)D * S, (long long)S * D);
  // 8. out = tmp @ Wqo + bqo — gemm8p
  gemm8p<0><<<dim3(32, 8, 1), 512, 98304, stream>>>(
      tmp, wqoT, bqo, out, nullptr, 8192, 1024, 1024, 0, 0, 0);
}

// Round 14
// 268.049 us; speedup vs baseline: 1.0259x; 1.0164x over previous
//
#include <hip/hip_runtime.h>

typedef unsigned short u16;
typedef unsigned int u32;
typedef signed char i8;
typedef __bf16 bf16x8 __attribute__((ext_vector_type(8)));
typedef float f32x4 __attribute__((ext_vector_type(4)));
typedef int i32x4 __attribute__((ext_vector_type(4)));
typedef i8 i8x4 __attribute__((ext_vector_type(4)));
typedef u16 u16x8 __attribute__((ext_vector_type(8)));

#define AS1(p) ((const __attribute__((address_space(1))) void*)(p))
#define AS3(p) ((__attribute__((address_space(3))) void*)(p))

__device__ __forceinline__ u16 f2bf(float x) {
  u32 u = __float_as_uint(x);
  u32 r = u + 0x7fffu + ((u >> 16) & 1u);
  return (u16)(r >> 16);
}
__device__ __forceinline__ float bf2f(u16 h) {
  return __uint_as_float(((u32)h) << 16);
}

// ---------------------------------------------------------------------------
// i8 dual-split quantizer: x ~= s*(h + l/256), |err| <= s/512.
// ---------------------------------------------------------------------------
#define S_IN (8.0f / 127.0f)
#define S_W (0.25f / 127.0f)
#define S_QK (8.0f / 127.0f)
#define INV_S_IN (127.0f / 8.0f)
#define INV_S_W (508.0f)
#define INV_S_QK (127.0f / 8.0f)

__device__ __forceinline__ int2 q8i(float x, float inv_s) {
  float t = fminf(fmaxf(x * inv_s, -126.99f), 126.99f);
  float hf = rintf(t);
  float lf = fminf(fmaxf(rintf((t - hf) * 256.0f), -127.0f), 127.0f);
  return make_int2((int)hf, (int)lf);
}

// ---------------------------------------------------------------------------
// prep_all: one launch fusing three independent preprocessing stages.
// ---------------------------------------------------------------------------
__global__ __launch_bounds__(256) void prep_all(
    const float* __restrict__ q, const float* __restrict__ k,
    const float* __restrict__ value, const float* __restrict__ Wq,
    const float* __restrict__ Wo, i8* __restrict__ qh, i8* __restrict__ ql,
    i8* __restrict__ kh, i8* __restrict__ kl, u16* __restrict__ valT,
    i8* __restrict__ wqt_h, i8* __restrict__ wqt_l, u16* __restrict__ wot,
    u16* __restrict__ wq_b) {
  __shared__ float tileA[32][33];
  __shared__ float tileB[32][33];
  const int bid = blockIdx.x;
  const int tid = threadIdx.x;
  const int D = 1024;

  if (bid < 8192) {
    const int bx = bid & 31;
    const int by = (bid >> 5) & 63;
    const int bz = bid >> 11;
    const int tx = tid & 31, ty = tid >> 5;
    const int c0 = bx * 32, r0 = by * 32;
    const size_t zi = (size_t)bz * 2048 * 1024;
#pragma unroll
    for (int i = ty; i < 32; i += 8)
      tileA[i][tx] = value[zi + (size_t)(r0 + i) * D + (c0 + tx)];
    __syncthreads();
#pragma unroll
    for (int i = ty; i < 32; i += 8)
      valT[zi + (size_t)(c0 + i) * 2048 + (r0 + tx)] = f2bf(tileA[tx][i]);
  } else if (bid < 10240) {
    const int b2 = bid - 8192;
    const int n4 = 2097152;
    const int stride = 2048 * 256;
    for (int i = b2 * 256 + tid; i < n4; i += stride) {
      float4 x = ((const float4*)q)[i];
      float xs[4] = {x.x, x.y, x.z, x.w};
      i8x4 h, l;
#pragma unroll
      for (int e = 0; e < 4; ++e) {
        int2 r = q8i(xs[e], INV_S_IN);
        h[e] = (i8)r.x;
        l[e] = (i8)r.y;
      }
      ((i8x4*)qh)[i] = h;
      ((i8x4*)ql)[i] = l;
      x = ((const float4*)k)[i];
      float ys[4] = {x.x, x.y, x.z, x.w};
#pragma unroll
      for (int e = 0; e < 4; ++e) {
        int2 r = q8i(ys[e], INV_S_IN);
        h[e] = (i8)r.x;
        l[e] = (i8)r.y;
      }
      ((i8x4*)kh)[i] = h;
      ((i8x4*)kl)[i] = l;
    }
  } else {
    const int r = bid - 10240;
    const int bx = r & 31, by = r >> 5;
    const int tx = tid & 31, ty = tid >> 5;
    const int c0 = bx * 32, r0 = by * 32;
#pragma unroll
    for (int i = ty; i < 32; i += 8) {
      float xq = Wq[(size_t)(r0 + i) * D + c0 + tx];
      tileA[i][tx] = xq;
      wq_b[(size_t)(r0 + i) * D + c0 + tx] = f2bf(xq);
      tileB[i][tx] = Wo[(size_t)(r0 + i) * D + c0 + tx];
    }
    __syncthreads();
#pragma unroll
    for (int i = ty; i < 32; i += 8) {
      float x = tileA[tx][i];
      int2 rr = q8i(x, INV_S_W);
      size_t o = (size_t)(c0 + i) * D + r0 + tx;
      wqt_h[o] = (i8)rr.x;
      wqt_l[o] = (i8)rr.y;
      wot[o] = f2bf(tileB[tx][i]);
    }
  }
}

// bqo[f] = sum_e bq[e]*Wo[e][f] + bo[f]   via wot (Wo^T bf16).
__global__ __launch_bounds__(256) void bqo_kernel(const float* __restrict__ bq,
                                                  const u16* __restrict__ wot,
                                                  const float* __restrict__ bo,
                                                  float* __restrict__ bqo,
                                                  int D) {
  const int f = blockIdx.x * 4 + (threadIdx.x >> 6);
  const int lane = threadIdx.x & 63;
  const u16* wr_ = wot + (size_t)f * D;
  float s = 0.f;
  for (int e = lane; e < D; e += 64) s += bq[e] * bf2f(wr_[e]);
#pragma unroll
  for (int off = 32; off; off >>= 1) s += __shfl_xor(s, off);
  if (lane == 0) bqo[f] = s + bo[f];
}

// ---------------------------------------------------------------------------
// 128x128 2-barrier GEMM (only for the tiny Wqo GEMM).
// ---------------------------------------------------------------------------
template <int EPI>
__global__ __launch_bounds__(256, 2) void gemm_bt(
    const u16* __restrict__ Ah, const u16* __restrict__ Bh,
    const float* __restrict__ bias, float* __restrict__ Cf,
    u16* __restrict__ Ch, int M, int N, int K,
    long long sA, long long sB, long long sC) {
  __shared__ alignas(16) u16 As[128 * 32];
  __shared__ alignas(16) u16 Bs[128 * 32];

  const int t = threadIdx.x;
  const int lane = t & 63;
  const int w = t >> 6;
  const int wr = w >> 1, wc = w & 1;

  const long long zb = blockIdx.z;
  const u16* pA = Ah + zb * sA;
  const u16* pB = Bh + zb * sB;

  const int m0 = blockIdx.x * 128;
  const int n0 = blockIdx.y * 128;

  f32x4 acc[4][4] = {};

  const int row0 = t >> 2;
  const int colS = (t & 3) * 8;
  const int lds0 = (t & ~63) * 8;
  const int lds1 = (256 + (t & ~63)) * 8;

  const size_t aoff0 = (size_t)(m0 + row0) * K + colS;
  const size_t aoff1 = (size_t)(m0 + row0 + 64) * K + colS;
  const size_t boff0 = (size_t)(n0 + row0) * K + colS;
  const size_t boff1 = (size_t)(n0 + row0 + 64) * K + colS;

  for (int k0 = 0; k0 < K; k0 += 32) {
    __syncthreads();
    __builtin_amdgcn_global_load_lds(AS1(pA + aoff0 + k0), AS3(&As[lds0]), 16, 0, 0);
    __builtin_amdgcn_global_load_lds(AS1(pA + aoff1 + k0), AS3(&As[lds1]), 16, 0, 0);
    __builtin_amdgcn_global_load_lds(AS1(pB + boff0 + k0), AS3(&Bs[lds0]), 16, 0, 0);
    __builtin_amdgcn_global_load_lds(AS1(pB + boff1 + k0), AS3(&Bs[lds1]), 16, 0, 0);
    __syncthreads();

    const int fr = lane & 15;
    const int kc = (lane >> 4) * 8;
    bf16x8 a[4], b[4];
#pragma unroll
    for (int i = 0; i < 4; ++i)
      a[i] = *(const bf16x8*)&As[(wr * 64 + i * 16 + fr) * 32 + kc];
#pragma unroll
    for (int j = 0; j < 4; ++j)
      b[j] = *(const bf16x8*)&Bs[(wc * 64 + j * 16 + fr) * 32 + kc];
#pragma unroll
    for (int i = 0; i < 4; ++i)
#pragma unroll
      for (int j = 0; j < 4; ++j)
        acc[i][j] = __builtin_amdgcn_mfma_f32_16x16x32_bf16(a[i], b[j], acc[i][j], 0, 0, 0);
  }

  const int er = (lane >> 4) * 4;
  const int ec = lane & 15;
#pragma unroll
  for (int j = 0; j < 4; ++j) {
    const int gcol = n0 + wc * 64 + j * 16 + ec;
    const float bv = bias ? bias[gcol] : 0.0f;
#pragma unroll
    for (int i = 0; i < 4; ++i) {
      const int grow0 = m0 + wr * 64 + i * 16 + er;
#pragma unroll
      for (int r = 0; r < 4; ++r) {
        const float x = acc[i][j][r] + bv;
        const size_t off = (size_t)zb * sC + (size_t)(grow0 + r) * N + gcol;
        if constexpr (EPI == 0) Cf[off] = x;
        else Ch[off] = f2bf(x);
      }
    }
  }
}

// ---------------------------------------------------------------------------
// gemm8i v5: i8 dual-split GEMM, 128x128 tile, BK=64, 16x16x64 i8 MFMA.
// 256 threads (4 waves, 2M x 2N, 64x64/wave). LDS 64KB (2 buf x 32KB) ->
// 2 blocks/CU: two independent barrier domains so one block's compute hides
// the other's barrier/drain stalls (m114 TLP mechanism). Same linear-dest /
// swizzled-source staging, conflict-free 16-row reads, identical per-element
// K-accumulation order (i32 exact -> absmax invariant).
// EPI: 0 = f32 out, 2 = i8 h/l split out (re-quantized with INV_S_QK).
// ---------------------------------------------------------------------------
// Stage a 16KB region (128 rows x 128B) as 4 instrs; linear LDS dest.
#define STG4_I(DSTBASE, SH, SL, ROWBASE, KREAL)                                \
  do {                                                                         \
    _Pragma("unroll") for (int p_ = 0; p_ < 4; ++p_) {                         \
      const i8* s_ = (sc < 4 ? (SH) : (SL)) +                                  \
                     (size_t)((ROWBASE) + p_ * 32 + sr) * K + (KREAL) +        \
                     ((sc & 3) << 4);                                          \
      __builtin_amdgcn_global_load_lds(                                        \
          AS1(s_), AS3(&lds8[(DSTBASE) + p_ * 4096 + ldsB]), 16, 0, 0);        \
    }                                                                          \
  } while (0)

#define LDA_I5(BUF)                                                            \
  do {                                                                         \
    const int base_ = (BUF) * 32768;                                           \
    _Pragma("unroll") for (int i_ = 0; i_ < 4; ++i_) {                         \
      const int r_ = wr * 64 + i_ * 16 + fr;                                   \
      ah[i_] = *(const i32x4*)&lds8[base_ + r_ * 128 + ((ksl ^ (r_ & 7)) << 4)]; \
      al[i_] = *(const i32x4*)&lds8[base_ + r_ * 128 + (((4 + ksl) ^ (r_ & 7)) << 4)]; \
    }                                                                          \
  } while (0)

#define LDB_I5(BUF)                                                            \
  do {                                                                         \
    const int base_ = (BUF) * 32768 + 16384;                                   \
    _Pragma("unroll") for (int j_ = 0; j_ < 4; ++j_) {                         \
      const int r_ = wc * 64 + j_ * 16 + fr;                                   \
      bh[j_] = *(const i32x4*)&lds8[base_ + r_ * 128 + ((ksl ^ (r_ & 7)) << 4)]; \
      bl[j_] = *(const i32x4*)&lds8[base_ + r_ * 128 + (((4 + ksl) ^ (r_ & 7)) << 4)]; \
    }                                                                          \
  } while (0)

#define MMA_I5()                                                               \
  do {                                                                         \
    _Pragma("unroll") for (int j_ = 0; j_ < 4; ++j_) {                         \
      _Pragma("unroll") for (int i_ = 0; i_ < 4; ++i_) {                       \
        accH[i_][j_] = __builtin_amdgcn_mfma_i32_16x16x64_i8(                  \
            ah[i_], bh[j_], accH[i_][j_], 0, 0, 0);                            \
        accX[i_][j_] = __builtin_amdgcn_mfma_i32_16x16x64_i8(                  \
            ah[i_], bl[j_], accX[i_][j_], 0, 0, 0);                            \
        accX[i_][j_] = __builtin_amdgcn_mfma_i32_16x16x64_i8(                  \
            al[i_], bh[j_], accX[i_][j_], 0, 0, 0);                            \
      }                                                                        \
    }                                                                          \
  } while (0)

template <int EPI>
__global__ __launch_bounds__(256, 2) void gemm8i(
    const i8* __restrict__ Ah, const i8* __restrict__ Al,
    const i8* __restrict__ Bh, const i8* __restrict__ Bl,
    const float* __restrict__ bias, float sAB, float* __restrict__ Cf,
    i8* __restrict__ Ch, i8* __restrict__ Cl, int M, int N, int K,
    long long sA, long long sB, long long sC) {
  extern __shared__ i8 lds8[];

  const int tt = threadIdx.x;
  const int lane = tt & 63;
  const int wv = tt >> 6;
  const int wr = wv >> 1;  // 0..1 (M-group of 64 rows)
  const int wc = wv & 1;   // 0..1 (N-group of 64 cols)
  const int fr = lane & 15;
  const int ksl = lane >> 4;  // 0..3

  const long long zb = blockIdx.z;
  const i8* pAh = Ah + zb * sA;
  const i8* pAl = Al + zb * sA;
  const i8* pBh = Bh + zb * sB;
  const i8* pBl = Bl + zb * sB;
  const int m0 = blockIdx.x * 128;
  const int n0 = blockIdx.y * 128;

  const int sr = tt >> 3;            // 0..31
  const int sc = (tt & 7) ^ (sr & 7);
  const int ldsB = (tt & ~63) * 16;  // bytes; linear dest

  i32x4 accH[4][4] = {};
  i32x4 accX[4][4] = {};
  i32x4 ah[4], al[4], bh[4], bl[4];

  const int NT = K / 64;

  // prologue: t0 -> buf0 (8 loads), t1 -> buf1 (8 loads); drain t0.
  STG4_I(0, pAh, pAl, m0, 0);
  STG4_I(16384, pBh, pBl, n0, 0);
  STG4_I(32768, pAh, pAl, m0, 64);
  STG4_I(32768 + 16384, pBh, pBl, n0, 64);
  asm volatile("s_waitcnt vmcnt(8)" ::: "memory");
  __builtin_amdgcn_s_barrier();

  for (int it = 0; it < NT; ++it) {
    const int cur = it & 1;
    const int nb = cur * 32768;
    const int kf = (it + 2 < NT ? it + 2 : NT - 1) * 64;

    LDA_I5(cur);
    LDB_I5(cur);
    MMA_I5();
    asm volatile("s_waitcnt lgkmcnt(0)" ::: "memory");
    __builtin_amdgcn_s_barrier();          // all waves done reading buf(cur)
    STG4_I(nb, pAh, pAl, m0, kf);          // t+2 -> buf(cur)
    STG4_I(nb + 16384, pBh, pBl, n0, kf);
    asm volatile("s_waitcnt vmcnt(8)" ::: "memory");  // t+1 landed
    __builtin_amdgcn_s_barrier();
  }

  // epilogue: C/D map col=lane&15, row=(lane>>4)*4+reg
  const int er = (lane >> 4) * 4;
  const int ec = lane & 15;
#pragma unroll
  for (int i = 0; i < 4; ++i) {
    const int grow0 = m0 + wr * 64 + i * 16 + er;
#pragma unroll
    for (int j = 0; j < 4; ++j) {
      const int gcol = n0 + wc * 64 + j * 16 + ec;
      const float bv = bias ? bias[gcol] : 0.0f;
#pragma unroll
      for (int r = 0; r < 4; ++r) {
        const float x =
            sAB * ((float)accH[i][j][r] + (float)accX[i][j][r] * 0.00390625f) + bv;
        const size_t off = (size_t)zb * sC + (size_t)(grow0 + r) * N + gcol;
        if constexpr (EPI == 0) {
          Cf[off] = x;  // f32 score (f16 failed: max|s|~176, ulp 0.125)
        } else {
          int2 qq = q8i(x, INV_S_QK);
          Ch[off] = (i8)qq.x;
          Cl[off] = (i8)qq.y;
        }
      }
    }
  }
}

// ---------------------------------------------------------------------------
// gemm8p v5: plain-bf16 128x128 tile, BK=64, 256 thr (4 waves 2x2, 64x64/wave),
// LDS 64KB -> 2 blocks/CU. Same TLP rationale as gemm8i v5.
// ---------------------------------------------------------------------------
#define STG4_P(DSTBASE, SRC, ROWBASE, KREAL)                                   \
  do {                                                                         \
    _Pragma("unroll") for (int p_ = 0; p_ < 4; ++p_) {                         \
      const u16* s_ = (SRC) + (size_t)((ROWBASE) + p_ * 32 + sr) * K +         \
                      (KREAL) + (sc << 3);                                     \
      __builtin_amdgcn_global_load_lds(                                        \
          AS1(s_), AS3(&lds[(DSTBASE) + p_ * 2048 + ldsW]), 16, 0, 0);         \
    }                                                                          \
  } while (0)

#define LDA_P5(BUF, S, DST)                                                    \
  do {                                                                         \
    const int base_ = (BUF) * 16384;                                           \
    _Pragma("unroll") for (int i_ = 0; i_ < 4; ++i_) {                         \
      const int r_ = wr * 64 + i_ * 16 + fr;                                   \
      DST[i_] = *(const bf16x8*)&lds[base_ + r_ * 64 + (((((S) * 4 + ksl)) ^ (r_ & 7)) << 3)]; \
    }                                                                          \
  } while (0)

#define LDB_P5(BUF, S, DST)                                                    \
  do {                                                                         \
    const int base_ = (BUF) * 16384 + 8192;                                    \
    _Pragma("unroll") for (int j_ = 0; j_ < 4; ++j_) {                         \
      const int r_ = wc * 64 + j_ * 16 + fr;                                   \
      DST[j_] = *(const bf16x8*)&lds[base_ + r_ * 64 + (((((S) * 4 + ksl)) ^ (r_ & 7)) << 3)]; \
    }                                                                          \
  } while (0)

#define MMA_P5(A_, B_)                                                         \
  do {                                                                         \
    _Pragma("unroll") for (int i_ = 0; i_ < 4; ++i_) {                         \
      _Pragma("unroll") for (int j_ = 0; j_ < 4; ++j_) {                       \
        acc[i_][j_] = __builtin_amdgcn_mfma_f32_16x16x32_bf16(                 \
            A_[i_], B_[j_], acc[i_][j_], 0, 0, 0);                             \
      }                                                                        \
    }                                                                          \
  } while (0)

template <int EPI>
__global__ __launch_bounds__(256, 2) void gemm8p(
    const u16* __restrict__ A, const u16* __restrict__ B,
    const float* __restrict__ bias, float* __restrict__ Cf,
    u16* __restrict__ Ch, int M, int N, int K,
    long long sA, long long sB, long long sC) {
  extern __shared__ u16 lds[];

  const int tt = threadIdx.x;
  const int lane = tt & 63;
  const int wv = tt >> 6;
  const int wr = wv >> 1;  // 0..1
  const int wc = wv & 1;   // 0..1
  const int fr = lane & 15;
  const int ksl = lane >> 4;

  const long long zb = blockIdx.z;
  const u16* pA = A + zb * sA;
  const u16* pB = B + zb * sB;
  const int m0 = blockIdx.x * 128;
  const int n0 = blockIdx.y * 128;

  const int sr = tt >> 3;
  const int sc = (tt & 7) ^ (sr & 7);
  const int ldsW = (tt & ~63) * 8;  // elements; linear dest

  f32x4 acc[4][4] = {};
  bf16x8 a0[4], a1[4], b0[4], b1[4];

  const int NT = K / 64;

  // prologue: t0 -> buf0, t1 -> buf1 (8 loads each); drain t0.
  STG4_P(0, pA, m0, 0);
  STG4_P(8192, pB, n0, 0);
  STG4_P(16384, pA, m0, 64);
  STG4_P(16384 + 8192, pB, n0, 64);
  asm volatile("s_waitcnt vmcnt(8)" ::: "memory");
  __builtin_amdgcn_s_barrier();

  for (int it = 0; it < NT; ++it) {
    const int cur = it & 1;
    const int nb = cur * 16384;
    const int kf = (it + 2 < NT ? it + 2 : NT - 1) * 64;

    LDA_P5(cur, 0, a0);
    LDB_P5(cur, 0, b0);
    LDA_P5(cur, 1, a1);
    LDB_P5(cur, 1, b1);
    MMA_P5(a0, b0);
    MMA_P5(a1, b1);
    asm volatile("s_waitcnt lgkmcnt(0)" ::: "memory");
    __builtin_amdgcn_s_barrier();
    STG4_P(nb, pA, m0, kf);
    STG4_P(nb + 8192, pB, n0, kf);
    asm volatile("s_waitcnt vmcnt(8)" ::: "memory");  // t+1 landed
    __builtin_amdgcn_s_barrier();
  }

  const int er = (lane >> 4) * 4;
  const int ec = lane & 15;
#pragma unroll
  for (int i = 0; i < 4; ++i) {
    const int grow0 = m0 + wr * 64 + i * 16 + er;
#pragma unroll
    for (int j = 0; j < 4; ++j) {
      const int gcol = n0 + wc * 64 + j * 16 + ec;
      const float bv = bias ? bias[gcol] : 0.0f;
#pragma unroll
      for (int r = 0; r < 4; ++r) {
        const float x = acc[i][j][r] + bv;
        const size_t off = (size_t)zb * sC + (size_t)(grow0 + r) * N + gcol;
        if constexpr (EPI == 0) Cf[off] = x;
        else Ch[off] = f2bf(x);
      }
    }
  }
}

// ---------------------------------------------------------------------------
// Row softmax over f32 scores, vectorized: in-place f32 weights + bf16 P.
// ---------------------------------------------------------------------------
__global__ __launch_bounds__(256) void softmax_rows_v(float* __restrict__ S,
                                                      u16* __restrict__ P) {
  const int T = 2048;
  const size_t row = blockIdx.x;
  float* sr = S + row * T;
  u16* prow = P + row * T;
  const int t = threadIdx.x;
  const int w = t >> 6, lane = t & 63;
  __shared__ float red[8];

  float4 r0 = ((const float4*)(sr + t * 8))[0];
  float4 r1 = ((const float4*)(sr + t * 8))[1];
  float v[8] = {r0.x, r0.y, r0.z, r0.w, r1.x, r1.y, r1.z, r1.w};
  float mx = -1e30f;
#pragma unroll
  for (int i = 0; i < 8; ++i) mx = fmaxf(mx, v[i]);
#pragma unroll
  for (int off = 32; off; off >>= 1) mx = fmaxf(mx, __shfl_xor(mx, off));
  if (lane == 0) red[w] = mx;
  __syncthreads();
  mx = fmaxf(fmaxf(red[0], red[1]), fmaxf(red[2], red[3]));

  float s = 0.f;
#pragma unroll
  for (int i = 0; i < 8; ++i) {
    v[i] = __expf(v[i] - mx);
    s += v[i];
  }
#pragma unroll
  for (int off = 32; off; off >>= 1) s += __shfl_xor(s, off);
  if (lane == 0) red[4 + w] = s;
  __syncthreads();
  s = (red[4] + red[5]) + (red[6] + red[7]);
  const float inv = 1.0f / s;

  u16x8 pv;
#pragma unroll
  for (int i = 0; i < 8; ++i) {
    v[i] *= inv;
    pv[i] = f2bf(v[i]);
  }
  float4* wr4 = (float4*)(sr + t * 8);
  wr4[0] = make_float4(v[0], v[1], v[2], v[3]);
  wr4[1] = make_float4(v[4], v[5], v[6], v[7]);
  ((u16x8*)prow)[t] = pv;
}

// ---------------------------------------------------------------------------
extern "C" void kernel_launch(void* const* d_in, const int* in_sizes, int n_in,
                              void* d_out, int out_size, void* d_ws,
                              size_t ws_size, hipStream_t stream) {
  (void)in_sizes; (void)n_in; (void)out_size; (void)ws_size;
  const float* query = (const float*)d_in[0];
  const float* key   = (const float*)d_in[1];
  const float* value = (const float*)d_in[2];
  const float* Wq    = (const float*)d_in[3];
  const float* bq    = (const float*)d_in[4];
  const float* Wo    = (const float*)d_in[5];
  const float* bo    = (const float*)d_in[6];

  const int S = 2048, D = 1024;
  const size_t n = (size_t)4 * S * D;   // 8,388,608 elements

  float* out = (float*)d_out;           // (B,S,D) f32, 32MB
  float* wts = out + n;                 // (B,S,T) f32 scores/weights, 64MB

  char* ws = (char*)d_ws;
  i8* wqt_h = (i8*)(ws);                     // 1MB  Wq^T hi (i8)
  i8* wqt_l = (i8*)(ws + (1ull << 20));      // 1MB  Wq^T lo
  u16* wot  = (u16*)(ws + (2ull << 20));     // 2MB  Wo^T bf16
  u16* wq_b = (u16*)(ws + (4ull << 20));     // 2MB  Wq bf16
  u16* wqoT = (u16*)(ws + (6ull << 20));     // 2MB  (Wq@Wo)^T bf16
  float* bqo = (float*)(ws + (8ull << 20));  // 4KB
  i8* QKh = (i8*)(ws + (9ull << 20));        // 16MB  [Q;K] hi
  i8* QKl = (i8*)(ws + (25ull << 20));       // 16MB  [Q;K] lo
  u16* tmp = (u16*)(ws + (41ull << 20));     // 16MB  P@value^T (total ws 57MB)
  u16* P = (u16*)(ws + (9ull << 20));        // 32MB overlay QKh+QKl (dead)

  // scratch in d_out: wts region holds input splits until score GEMM writes;
  // out region holds value^T until the final GEMM writes.
  i8* ah = (i8*)wts;        // [q;k] hi, 16MB (dead after proj GEMM)
  i8* al = ah + 2 * n;      // [q;k] lo, 16MB
  u16* valT = (u16*)out;    // (B, D, T) bf16, 16MB (dead after PV)

  hipFuncSetAttribute((const void*)&gemm8i<2>,
                      hipFuncAttributeMaxDynamicSharedMemorySize, 65536);
  hipFuncSetAttribute((const void*)&gemm8i<0>,
                      hipFuncAttributeMaxDynamicSharedMemorySize, 65536);
  hipFuncSetAttribute((const void*)&gemm8p<1>,
                      hipFuncAttributeMaxDynamicSharedMemorySize, 65536);
  hipFuncSetAttribute((const void*)&gemm8p<0>,
                      hipFuncAttributeMaxDynamicSharedMemorySize, 65536);

  // 1. fused prep: value^T + split q,k + weight prep (11264 blocks)
  prep_all<<<11264, 256, 0, stream>>>(query, key, value, Wq, Wo, ah, al,
                                      ah + n, al + n, valT, wqt_h, wqt_l, wot,
                                      wq_b);
  // 2. WqoT = (Wq@Wo)^T bf16
  gemm_bt<1><<<dim3(8, 8, 1), 256, 0, stream>>>(
      wot, wq_b, nullptr, nullptr, wqoT, 1024, 1024, 1024, 0, 0, 0);
  // 3. bqo = bq@Wo + bo
  bqo_kernel<<<256, 256, 0, stream>>>(bq, wot, bo, bqo, D);
  // 4. [Q;K] = [q;k] @ Wq + bq  (i8 dual-split GEMM, i8 split out)
  gemm8i<2><<<dim3(128, 8, 1), 256, 65536, stream>>>(
      ah, al, wqt_h, wqt_l, bq, S_IN * S_W, nullptr, QKh, QKl,
      16384, 1024, 1024, 0, 0, 0);
  // 5. score = Q @ K^T (i8 dual-split GEMM, f32 out into weights region)
  gemm8i<0><<<dim3(16, 16, 4), 256, 65536, stream>>>(
      QKh, QKl, QKh + n, QKl + n, nullptr, S_QK * S_QK, wts, nullptr, nullptr,
      2048, 2048, 1024, (long long)S * D, (long long)S * D, (long long)S * S);
  // 6. softmax rows (in-place, vectorized) + bf16 P
  softmax_rows_v<<<8192, 256, 0, stream>>>(wts, P);
  // 7. tmp = P @ value^T — gemm8p
  gemm8p<1><<<dim3(16, 8, 4), 256, 65536, stream>>>(
      P, valT, nullptr, nullptr, tmp, 2048, 1024, 2048, (long long)S * S,
      (long long)D * S, (long long)S * D);
  // 8. out = tmp @ Wqo + bqo — gemm8p
  gemm8p<0><<<dim3(64, 8, 1), 256, 65536, stream>>>(
      tmp, wqoT, bqo, out, nullptr, 8192, 1024, 1024, 0, 0, 0);
}